// Round 5
// baseline (670.669 us; speedup 1.0000x reference)
//
#include <hip/hip_runtime.h>
#include <math.h>

#define B_    8
#define C_    128
#define D_    128
#define L_    4096
#define NPOS_ 32768
#define NC_   256          // scan chunks per batch
#define S_    16           // chunk length
#define MFL_  1048576
#define NBLK_ 512u

typedef __attribute__((ext_vector_type(8))) short short8;
typedef __attribute__((ext_vector_type(4))) float f32x4;

__device__ __forceinline__ float siluf(float x) { return x / (1.f + __expf(-x)); }
__device__ __forceinline__ float softplusf(float x) {
    if (x > 20.f) return x;
    return __logf(1.f + __expf(x));
}
__device__ __forceinline__ unsigned short f2bf(float f) {
    unsigned int u = __float_as_uint(f);
    u = (u + 0x7FFFu + ((u >> 16) & 1u)) >> 16;
    return (unsigned short)u;
}
__device__ __forceinline__ float bf2f(unsigned short h) {
    return __uint_as_float(((unsigned int)h) << 16);
}
__device__ __forceinline__ void scan_as(float dl, const float* Ar, bool fast, float* a) {
    if (fast) {
        float e1 = __expf(-dl);
        a[0] = e1;
        a[1] = e1 * e1;
        a[2] = a[1] * e1;
        a[3] = a[1] * a[1];
        a[4] = a[3] * e1;
        a[5] = a[3] * a[1];
        a[6] = a[5] * e1;
        a[7] = a[3] * a[3];
    } else {
        #pragma unroll
        for (int n = 0; n < 8; ++n) a[n] = __expf(dl * Ar[n]);
    }
}

// Device-scope grid barrier: 8 arrival cells + go flag per phase (64B stride).
// All 512 blocks are co-resident (LDS 57.5KB -> 2 blk/CU, launch_bounds caps VGPR).
__device__ __forceinline__ void gbar(unsigned int* bar, int phase) {
    __syncthreads();
    if (threadIdx.x == 0) {
        unsigned int* c = bar + phase * 16;
        __threadfence();
        __hip_atomic_fetch_add(&c[blockIdx.x & 7], 1u, __ATOMIC_ACQ_REL, __HIP_MEMORY_SCOPE_AGENT);
        if (blockIdx.x == 0) {
            unsigned int s;
            do {
                __builtin_amdgcn_s_sleep(1);
                s = 0;
                #pragma unroll
                for (int i = 0; i < 8; ++i)
                    s += __hip_atomic_load(&c[i], __ATOMIC_RELAXED, __HIP_MEMORY_SCOPE_AGENT);
            } while (s < NBLK_);
            __hip_atomic_store(&c[8], 1u, __ATOMIC_RELEASE, __HIP_MEMORY_SCOPE_AGENT);
        } else {
            while (__hip_atomic_load(&c[8], __ATOMIC_ACQUIRE, __HIP_MEMORY_SCOPE_AGENT) == 0u)
                __builtin_amdgcn_s_sleep(1);
        }
        __threadfence();
    }
    __syncthreads();
}

__global__ __launch_bounds__(256, 2) void mega(
        const float* __restrict__ x,
        const float* __restrict__ w1,
        const float* __restrict__ w2,
        const float* __restrict__ inW,
        const float* __restrict__ OW,
        const float* __restrict__ xpw,
        const float* __restrict__ dw,
        const float* __restrict__ cw,
        const float* __restrict__ cb,
        const float* __restrict__ dtw,
        const float* __restrict__ dtb,
        const float* __restrict__ A_log,
        const float* __restrict__ Dp,
        const float* __restrict__ gamma,
        const float* __restrict__ beta,
        const float* __restrict__ wout,
        unsigned short* __restrict__ inWb,
        unsigned short* __restrict__ OWb,
        unsigned short* __restrict__ xpwb,
        unsigned short* __restrict__ t1b,
        unsigned short* __restrict__ x2sb,
        unsigned short* __restrict__ x1cb,
        unsigned short* __restrict__ urawb,
        unsigned short* __restrict__ zb,
        unsigned short* __restrict__ usb,
        unsigned short* __restrict__ deltab,
        float* __restrict__ Bm,
        float* __restrict__ Cm,
        float* __restrict__ cA,
        float* __restrict__ cB,
        float* __restrict__ AgA,
        float* __restrict__ AgB,
        float* __restrict__ gcar,
        float* __restrict__ out,
        unsigned int* __restrict__ bar) {
    __shared__ __align__(16) char arena[57472];
    int t = threadIdx.x;

    // ================= P1: k1 (weight cvt + grouped 1x1), orig grid 1024 =================
    {
        float* xs = (float*)arena;
        for (int it2 = 0; it2 < 2; ++it2) {
            int obid = (int)blockIdx.x + it2 * 512;
            int i = obid * 51 + t;
            if (t < 51 && i < 52224) {
                if (i < 32768)      inWb[i] = f2bf(inW[i]);
                else if (i < 49152) OWb[i - 32768] = f2bf(OW[i - 32768]);
                else                xpwb[i - 49152] = f2bf(xpw[i - 49152]);
            }
        }
        int op = t & 63, ph = t >> 6;
        int g = op >> 4, o2 = (op & 15) * 2;
        const float* w1p = &w1[g * 1024 + o2 * 32];
        const float* w2p = &w2[g * 1024 + o2 * 32];
        float w1r[64], w2r[64];
        #pragma unroll
        for (int i = 0; i < 64; ++i) { w1r[i] = w1p[i]; w2r[i] = w2p[i]; }
        for (int it2 = 0; it2 < 2; ++it2) {
            int obid = (int)blockIdx.x + it2 * 512;
            int pos0 = obid * 32;
            for (int it = 0; it < 2; ++it) {
                int p0 = pos0 + it * 16;
                #pragma unroll
                for (int q = 0; q < 2; ++q) {
                    int fi = t * 2 + q;
                    *(float4*)&xs[fi * 4] = *(const float4*)&x[p0 * 128 + fi * 4];
                }
                __syncthreads();
                #pragma unroll
                for (int q = 0; q < 4; ++q) {
                    int pl = ph * 4 + q;
                    float a1 = 0.f, b1 = 0.f, a2 = 0.f, b2 = 0.f;
                    const float* xr = &xs[pl * 128 + g * 32];
                    #pragma unroll
                    for (int i4 = 0; i4 < 8; ++i4) {
                        float4 xv = *(const float4*)&xr[i4 * 4];
                        a1 += xv.x * w1r[i4*4]    + xv.y * w1r[i4*4+1]    + xv.z * w1r[i4*4+2]    + xv.w * w1r[i4*4+3];
                        b1 += xv.x * w1r[32+i4*4] + xv.y * w1r[32+i4*4+1] + xv.z * w1r[32+i4*4+2] + xv.w * w1r[32+i4*4+3];
                        a2 += xv.x * w2r[i4*4]    + xv.y * w2r[i4*4+1]    + xv.z * w2r[i4*4+2]    + xv.w * w2r[i4*4+3];
                        b2 += xv.x * w2r[32+i4*4] + xv.y * w2r[32+i4*4+1] + xv.z * w2r[32+i4*4+2] + xv.w * w2r[32+i4*4+3];
                    }
                    int pos = p0 + pl;
                    int db = pos * 128 + g * 32 + o2;
                    unsigned int u1 = (unsigned int)f2bf(a1) | ((unsigned int)f2bf(b1) << 16);
                    unsigned int u2 = (unsigned int)f2bf(siluf(a2)) | ((unsigned int)f2bf(siluf(b2)) << 16);
                    *(unsigned int*)&t1b[db]  = u1;
                    *(unsigned int*)&x2sb[db] = u2;
                }
                __syncthreads();
            }
        }
    }
    gbar(bar, 0);

    // ================= P2: k2 (dwconv 3x3 + silu), orig grid 1024 x 128 =================
    {
        int obid = (int)blockIdx.x * 2 + (t >> 7);
        int d = t & 127;
        float dwr[9];
        #pragma unroll
        for (int k = 0; k < 9; ++k) dwr[k] = dw[k * 128 + d];
        int wt = obid & 15, ht = (obid >> 4) & 7, b = obid >> 7;
        int h0 = ht * 8, w0 = wt * 4;
        float rows[10][6];
        #pragma unroll
        for (int r = 0; r < 10; ++r) {
            int hh = h0 - 1 + r;
            bool hv = (hh >= 0) && (hh < 64);
            #pragma unroll
            for (int c = 0; c < 6; ++c) {
                int w = w0 - 1 + c;
                bool wvv = (w >= 0) && (w < 64);
                rows[r][c] = (hv && wvv) ? bf2f(t1b[((b * 64 + hh) * 64 + w) * 128 + d]) : 0.f;
            }
        }
        #pragma unroll
        for (int hi = 0; hi < 8; ++hi) {
            #pragma unroll
            for (int wi = 0; wi < 4; ++wi) {
                float acc = rows[hi][wi]     * dwr[0] + rows[hi][wi+1]   * dwr[1] + rows[hi][wi+2]   * dwr[2]
                          + rows[hi+1][wi]   * dwr[3] + rows[hi+1][wi+1] * dwr[4] + rows[hi+1][wi+2] * dwr[5]
                          + rows[hi+2][wi]   * dwr[6] + rows[hi+2][wi+1] * dwr[7] + rows[hi+2][wi+2] * dwr[8];
                x1cb[((b * 64 + h0 + hi) * 64 + w0 + wi) * 128 + d] = f2bf(siluf(acc));
            }
        }
    }
    gbar(bar, 1);

    // ================= P3: k3 (in_proj MFMA), orig grid 1024 =================
    {
        unsigned short* Al = (unsigned short*)arena;            // 64*72
        unsigned short* Bl = (unsigned short*)(arena + 9216);   // 128*72
        int lane = t & 63, wv = t >> 6;
        int lanem = lane & 15, laneq = lane >> 4;
        for (int it2 = 0; it2 < 2; ++it2) {
            int obid = (int)blockIdx.x + it2 * 512;
            int pos0 = (obid >> 1) * 64;
            int half = obid & 1;
            const unsigned short* Bh = inWb + (size_t)half * 128 * 128;
            unsigned short* dst = half ? zb : urawb;
            f32x4 acc[8];
            #pragma unroll
            for (int i = 0; i < 8; ++i) acc[i] = (f32x4){0.f, 0.f, 0.f, 0.f};
            for (int kc = 0; kc < 2; ++kc) {
                #pragma unroll
                for (int q = 0; q < 2; ++q) {
                    int c = t + q * 256;
                    int row = c >> 3, col = c & 7;
                    *(int4*)&Al[row * 72 + col * 8] = *(const int4*)&x1cb[(pos0 + row) * 128 + kc * 64 + col * 8];
                }
                #pragma unroll
                for (int q = 0; q < 4; ++q) {
                    int c = t + q * 256;
                    int row = c >> 3, col = c & 7;
                    *(int4*)&Bl[row * 72 + col * 8] = *(const int4*)&Bh[row * 128 + kc * 64 + col * 8];
                }
                __syncthreads();
                #pragma unroll
                for (int ks = 0; ks < 2; ++ks) {
                    short8 af = *(const short8*)&Al[(wv * 16 + lanem) * 72 + ks * 32 + laneq * 8];
                    #pragma unroll
                    for (int ni = 0; ni < 8; ++ni) {
                        short8 bfr = *(const short8*)&Bl[(ni * 16 + lanem) * 72 + ks * 32 + laneq * 8];
                        acc[ni] = __builtin_amdgcn_mfma_f32_16x16x32_bf16(af, bfr, acc[ni], 0, 0, 0);
                    }
                }
                __syncthreads();
            }
            #pragma unroll
            for (int ni = 0; ni < 8; ++ni)
                #pragma unroll
                for (int r = 0; r < 4; ++r) {
                    int m = pos0 + wv * 16 + laneq * 4 + r;
                    int n = ni * 16 + lanem;
                    dst[m * 128 + n] = f2bf(acc[ni][r]);
                }
        }
    }
    gbar(bar, 2);

    // ================= P4: k45 (conv1d + x_proj + delta + scan ph1), orig grid 1024 =================
    {
        unsigned short* uA = (unsigned short*)arena;             // 32*136
        unsigned short* xB = (unsigned short*)(arena + 8704);    // 32*136
        float* xdb = (float*)(arena + 17408);                    // 32*36
        int d = t & 127, ph = t >> 7;
        float cw0 = cw[d * 3 + 0], cw1 = cw[d * 3 + 1], cw2 = cw[d * 3 + 2], cbr = cb[d];
        float dtwr[8];
        #pragma unroll
        for (int r = 0; r < 8; ++r) dtwr[r] = dtw[d * 8 + r];
        float dtbr = dtb[d];
        float Ar[8]; bool fast = true;
        #pragma unroll
        for (int n = 0; n < 8; ++n) {
            Ar[n] = -__expf(A_log[d * 8 + n]);
            fast = fast && (fabsf(Ar[n] + (float)(n + 1)) < 2e-3f);
        }
        int lane = t & 63, wv = t >> 6;
        int lanem = lane & 15, laneq = lane >> 4;
        int m0 = (wv & 1) * 16, n0 = (wv >> 1) * 16;
        for (int it2 = 0; it2 < 2; ++it2) {
            int obid = (int)blockIdx.x + it2 * 512;
            for (int i = t; i < 32 * 128; i += 256) {
                int n = i >> 7, k = i & 127;
                xB[n * 136 + k] = (n < 24) ? xpwb[n * 128 + k] : (unsigned short)0;
            }
            int gpos0 = obid * 32;
            int ll0 = (gpos0 & 4095) + ph * 16;
            int base = (gpos0 + ph * 16) * 128 + d;
            float ur0 = (ll0 >= 2) ? bf2f(urawb[base - 256]) : 0.f;
            float ur1 = (ll0 >= 1) ? bf2f(urawb[base - 128]) : 0.f;
            #pragma unroll
            for (int q = 0; q < 16; ++q) {
                float urq = bf2f(urawb[base + q * 128]);
                float v = siluf(ur0 * cw0 + ur1 * cw1 + urq * cw2 + cbr);
                unsigned short vb = f2bf(v);
                usb[base + q * 128] = vb;
                uA[(ph * 16 + q) * 136 + d] = vb;
                ur0 = ur1; ur1 = urq;
            }
            __syncthreads();
            f32x4 accx = (f32x4){0.f, 0.f, 0.f, 0.f};
            #pragma unroll
            for (int ks = 0; ks < 4; ++ks) {
                short8 af  = *(const short8*)&uA[(m0 + lanem) * 136 + ks * 32 + laneq * 8];
                short8 bfr = *(const short8*)&xB[(n0 + lanem) * 136 + ks * 32 + laneq * 8];
                accx = __builtin_amdgcn_mfma_f32_16x16x32_bf16(af, bfr, accx, 0, 0, 0);
            }
            #pragma unroll
            for (int r = 0; r < 4; ++r)
                xdb[(m0 + laneq * 4 + r) * 36 + n0 + lanem] = accx[r];
            __syncthreads();
            float h[8], ap[8];
            #pragma unroll
            for (int n = 0; n < 8; ++n) { h[n] = 0.f; ap[n] = 1.f; }
            #pragma unroll
            for (int q = 0; q < 16; ++q) {
                int pl = ph * 16 + q;
                const float* xrow = &xdb[pl * 36];
                float4 d0 = *(const float4*)&xrow[0];
                float4 d1 = *(const float4*)&xrow[4];
                float dt = dtbr + d0.x * dtwr[0] + d0.y * dtwr[1] + d0.z * dtwr[2] + d0.w * dtwr[3]
                                + d1.x * dtwr[4] + d1.y * dtwr[5] + d1.z * dtwr[6] + d1.w * dtwr[7];
                unsigned short dlb = f2bf(softplusf(dt));
                deltab[base + q * 128] = dlb;
                float dl = bf2f(dlb);
                float du = dl * bf2f(uA[pl * 136 + d]);
                float bmv[8];
                *(float4*)&bmv[0] = *(const float4*)&xrow[8];
                *(float4*)&bmv[4] = *(const float4*)&xrow[12];
                float a[8];
                scan_as(dl, Ar, fast, a);
                #pragma unroll
                for (int n = 0; n < 8; ++n) {
                    ap[n] *= a[n];
                    h[n] = a[n] * h[n] + du * bmv[n];
                }
            }
            int bH = gpos0 >> 12;
            int c  = ((gpos0 & 4095) >> 4) + ph;
            int obase = ((bH * NC_ + c) * 128 + d) * 8;
            *(float4*)&cA[obase]     = make_float4(ap[0], ap[1], ap[2], ap[3]);
            *(float4*)&cA[obase + 4] = make_float4(ap[4], ap[5], ap[6], ap[7]);
            *(float4*)&cB[obase]     = make_float4(h[0], h[1], h[2], h[3]);
            *(float4*)&cB[obase + 4] = make_float4(h[4], h[5], h[6], h[7]);
            if (t < 128) {
                int p = t >> 2, q = t & 3;
                float4 v = *(const float4*)&xdb[p * 36 + 8 + q * 4];
                int gp = gpos0 + p;
                if (q < 2) *(float4*)&Bm[gp * 8 + q * 4] = v;
                else       *(float4*)&Cm[gp * 8 + (q - 2) * 4] = v;
            }
            __syncthreads();   // protect uA/xdb reuse across it2
        }
    }
    gbar(bar, 3);

    // ================= P5: k6a (within-group prefix, in place), grid 512 =================
    {
        int id = (int)blockIdx.x * 256 + t;
        int dn = id & 1023;
        int grp = (id >> 10) & 15;
        int b = id >> 14;
        float Apre = 1.f, h = 0.f;
        int base = (b * NC_ + grp * 16) * 1024 + dn;
        #pragma unroll 4
        for (int j = 0; j < 16; ++j) {
            int idx = base + j * 1024;
            float a  = cA[idx];
            float bv = cB[idx];
            cA[idx] = Apre;
            cB[idx] = h;
            Apre *= a;
            h = a * h + bv;
        }
        int aidx = (b * 16 + grp) * 1024 + dn;
        AgA[aidx] = Apre;
        AgB[aidx] = h;
    }
    gbar(bar, 4);

    // ================= P6: k6b (scan over 16 group aggregates), orig grid 32 =================
    {
        if (blockIdx.x < 32) {
            int id = (int)blockIdx.x * 256 + t;
            int dn = id & 1023;
            int b = id >> 10;
            float h = 0.f;
            #pragma unroll
            for (int grp = 0; grp < 16; ++grp) {
                int idx = (b * 16 + grp) * 1024 + dn;
                float Ag = AgA[idx];
                float Bg = AgB[idx];
                gcar[idx] = h;
                h = Ag * h + Bg;
            }
        }
    }
    gbar(bar, 5);

    // ================= P7: k7f (scan replay + out_proj MFMA + LN + wout), grid 512 =================
    {
        unsigned short* yA = (unsigned short*)arena;             // [2][64][72]
        unsigned short* Bl = (unsigned short*)(arena + 18432);   // [128][72]
        float* xz = (float*)arena;                               // [64][148]
        float* woutL = (float*)(arena + 37888);                  // 4*1160
        float* gbL = (float*)(arena + 37888 + 18560);            // 256
        for (int idx = t; idx < 4096; idx += 256) {
            int g = idx >> 10, r = idx & 1023, o = r >> 5, i = r & 31;
            woutL[g * 1160 + o * 36 + i] = wout[idx];
        }
        if (t < 128) gbL[t] = gamma[t];
        else         gbL[t] = beta[t - 128];

        int d = t & 127, ph = t >> 7;
        int b = (int)blockIdx.x >> 6, cblk = (int)blockIdx.x & 63;
        float Ar[8]; bool fast = true;
        #pragma unroll
        for (int n = 0; n < 8; ++n) {
            Ar[n] = -__expf(A_log[d * 8 + n]);
            fast = fast && (fabsf(Ar[n] + (float)(n + 1)) < 2e-3f);
        }
        float Dpr = Dp[d];
        int ybase = (d >> 6) * (64 * 72) + (d & 63);
        for (int cc = 0; cc < 2; ++cc) {
            int cl = ph * 2 + cc;
            int c = cblk * 4 + cl;
            int cbase = ((b * NC_ + c) * 128 + d) * 8;
            float4 ap0 = *(const float4*)&cA[cbase];
            float4 ap1 = *(const float4*)&cA[cbase + 4];
            float4 bp0 = *(const float4*)&cB[cbase];
            float4 bp1 = *(const float4*)&cB[cbase + 4];
            int gbase = (b * 16 + (c >> 4)) * 1024 + d * 8;
            float4 g0 = *(const float4*)&gcar[gbase];
            float4 g1 = *(const float4*)&gcar[gbase + 4];
            float h[8] = { fmaf(g0.x, ap0.x, bp0.x), fmaf(g0.y, ap0.y, bp0.y),
                           fmaf(g0.z, ap0.z, bp0.z), fmaf(g0.w, ap0.w, bp0.w),
                           fmaf(g1.x, ap1.x, bp1.x), fmaf(g1.y, ap1.y, bp1.y),
                           fmaf(g1.z, ap1.z, bp1.z), fmaf(g1.w, ap1.w, bp1.w) };
            int base  = (b * L_ + c * S_) * 128 + d;
            int bbase = (b * L_ + c * S_) * 8;
            #pragma unroll
            for (int s = 0; s < S_; ++s) {
                float dl = bf2f(deltab[base + s * 128]);
                float uv = bf2f(usb[base + s * 128]);
                float zv = bf2f(zb[base + s * 128]);
                float du = dl * uv;
                float4 bm0 = *(const float4*)&Bm[bbase + s * 8];
                float4 bm1 = *(const float4*)&Bm[bbase + s * 8 + 4];
                float4 cm0 = *(const float4*)&Cm[bbase + s * 8];
                float4 cm1 = *(const float4*)&Cm[bbase + s * 8 + 4];
                float a[8];
                scan_as(dl, Ar, fast, a);
                h[0] = a[0] * h[0] + du * bm0.x;
                h[1] = a[1] * h[1] + du * bm0.y;
                h[2] = a[2] * h[2] + du * bm0.z;
                h[3] = a[3] * h[3] + du * bm0.w;
                h[4] = a[4] * h[4] + du * bm1.x;
                h[5] = a[5] * h[5] + du * bm1.y;
                h[6] = a[6] * h[6] + du * bm1.z;
                h[7] = a[7] * h[7] + du * bm1.w;
                float yv = h[0] * cm0.x + h[1] * cm0.y + h[2] * cm0.z + h[3] * cm0.w
                         + h[4] * cm1.x + h[5] * cm1.y + h[6] * cm1.z + h[7] * cm1.w;
                yv = (yv + uv * Dpr) * siluf(zv);
                yA[ybase + (cl * 16 + s) * 72] = f2bf(yv);
            }
        }
        __syncthreads();

        int lane = t & 63, wv = t >> 6;
        int lanem = lane & 15, laneq = lane >> 4;
        f32x4 acc[8];
        #pragma unroll
        for (int i = 0; i < 8; ++i) acc[i] = (f32x4){0.f, 0.f, 0.f, 0.f};
        for (int kc = 0; kc < 2; ++kc) {
            #pragma unroll
            for (int q = 0; q < 4; ++q) {
                int cidx = t + q * 256;
                int row = cidx >> 3, col = cidx & 7;
                *(int4*)&Bl[row * 72 + col * 8] = *(const int4*)&OWb[row * 128 + kc * 64 + col * 8];
            }
            __syncthreads();
            #pragma unroll
            for (int ks = 0; ks < 2; ++ks) {
                short8 af = *(const short8*)&yA[kc * (64 * 72) + (wv * 16 + lanem) * 72 + ks * 32 + laneq * 8];
                #pragma unroll
                for (int ni = 0; ni < 8; ++ni) {
                    short8 bfr = *(const short8*)&Bl[(ni * 16 + lanem) * 72 + ks * 32 + laneq * 8];
                    acc[ni] = __builtin_amdgcn_mfma_f32_16x16x32_bf16(af, bfr, acc[ni], 0, 0, 0);
                }
            }
            __syncthreads();
        }
        #pragma unroll
        for (int ni = 0; ni < 8; ++ni) {
            int ch = ni * 16 + lanem;
            int col = ch + ((ch >> 5) << 2);
            #pragma unroll
            for (int r = 0; r < 4; ++r)
                xz[(wv * 16 + laneq * 4 + r) * 148 + col] = bf2f(f2bf(acc[ni][r]));
        }
        __syncthreads();

        int g = t & 3, pos = t >> 2;
        int gpos = b * L_ + cblk * 64 + pos;
        const float* xrow0 = &xz[pos * 148 + g * 36];
        float v[32];
        #pragma unroll
        for (int i4 = 0; i4 < 8; ++i4) {
            float4 xv = *(const float4*)&xrow0[i4 * 4];
            v[i4*4+0] = xv.x; v[i4*4+1] = xv.y;
            v[i4*4+2] = xv.z; v[i4*4+3] = xv.w;
        }
        float s = 0.f, s2 = 0.f;
        #pragma unroll
        for (int i = 0; i < 32; ++i) { s += v[i]; s2 += v[i] * v[i]; }
        s  += __shfl_xor(s, 1, 64);  s  += __shfl_xor(s, 2, 64);
        s2 += __shfl_xor(s2, 1, 64); s2 += __shfl_xor(s2, 2, 64);
        float m = s * (1.f / 128.f);
        float var = s2 * (1.f / 128.f) - m * m;
        float rstd = rsqrtf(var + 1e-5f);
        #pragma unroll
        for (int i4 = 0; i4 < 8; ++i4) {
            ushort4 xv = *(const ushort4*)&x2sb[gpos * 128 + g * 32 + i4 * 4];
            unsigned short xa[4] = {xv.x, xv.y, xv.z, xv.w};
            #pragma unroll
            for (int k = 0; k < 4; ++k) {
                int e = g * 32 + i4 * 4 + k;
                float vv = (v[i4 * 4 + k] - m) * rstd * gbL[e] + gbL[128 + e];
                v[i4 * 4 + k] = vv * bf2f(xa[k]);
            }
        }
        const float* wg = &woutL[g * 1160];
        int obase = gpos * 128 + g * 32;
        #pragma unroll
        for (int ob = 0; ob < 8; ++ob) {
            float o4[4];
            #pragma unroll
            for (int oo = 0; oo < 4; ++oo) {
                int o = ob * 4 + oo;
                float acc2 = 0.f;
                #pragma unroll
                for (int i4 = 0; i4 < 8; ++i4) {
                    float4 wv4 = *(const float4*)&wg[o * 36 + i4 * 4];
                    acc2 += v[i4*4] * wv4.x + v[i4*4+1] * wv4.y
                          + v[i4*4+2] * wv4.z + v[i4*4+3] * wv4.w;
                }
                o4[oo] = acc2;
            }
            *(float4*)&out[obase + ob * 4] = make_float4(o4[0], o4[1], o4[2], o4[3]);
        }
    }
}

extern "C" void kernel_launch(void* const* d_in, const int* in_sizes, int n_in,
                              void* d_out, int out_size, void* d_ws, size_t ws_size,
                              hipStream_t stream) {
    (void)in_sizes; (void)n_in; (void)out_size; (void)ws_size;
    const float* x         = (const float*)d_in[0];
    const float* w1        = (const float*)d_in[1];
    const float* dw        = (const float*)d_in[2];
    const float* in_proj_w = (const float*)d_in[3];
    const float* conv1d_w  = (const float*)d_in[4];
    const float* conv1d_b  = (const float*)d_in[5];
    const float* x_proj_w  = (const float*)d_in[6];
    const float* dt_proj_w = (const float*)d_in[7];
    const float* dt_proj_b = (const float*)d_in[8];
    const float* A_log     = (const float*)d_in[9];
    const float* D_param   = (const float*)d_in[10];
    const float* out_proj_w= (const float*)d_in[11];
    const float* gamma     = (const float*)d_in[12];
    const float* beta      = (const float*)d_in[13];
    const float* w2        = (const float*)d_in[14];
    const float* wout      = (const float*)d_in[15];
    float* out = (float*)d_out;

    float* ws = (float*)d_ws;
    unsigned short* x2sb   = (unsigned short*)(ws);
    unsigned short* t1b    = (unsigned short*)(ws + 2  * (size_t)MFL_);
    unsigned short* x1cb   = (unsigned short*)(ws + 4  * (size_t)MFL_);
    unsigned short* urawb  = (unsigned short*)(ws + 6  * (size_t)MFL_);
    unsigned short* zb     = (unsigned short*)(ws + 8  * (size_t)MFL_);
    unsigned short* usb    = (unsigned short*)(ws + 14 * (size_t)MFL_);
    unsigned short* deltab = (unsigned short*)(ws + 16 * (size_t)MFL_);
    float* Bm    = ws + 18 * (size_t)MFL_;            // 262144
    float* Cm    = Bm + (size_t)NPOS_ * 8;            // 262144
    float* cA    = Cm + (size_t)NPOS_ * 8;            // 2M fl
    float* cB    = cA + 2 * (size_t)MFL_;             // 2M fl
    float* scanw = cB + 2 * (size_t)MFL_;
    float* AgA   = scanw;                             // 131072 fl
    float* AgB   = scanw + 131072;                    // 131072 fl
    float* gcar  = scanw + 262144;                    // 131072 fl
    unsigned short* inWb = (unsigned short*)(scanw + 2 * (size_t)MFL_);
    unsigned short* OWb  = inWb + 32768;
    unsigned short* xpwb = OWb + 16384;
    unsigned int* bar = (unsigned int*)(ws + 26 * (size_t)MFL_ / 1);  // 104 MB point, past all buffers

    hipMemsetAsync(bar, 0, 6 * 16 * sizeof(unsigned int), stream);
    mega<<<512, 256, 0, stream>>>(x, w1, w2, in_proj_w, out_proj_w, x_proj_w, dw,
                                  conv1d_w, conv1d_b, dt_proj_w, dt_proj_b, A_log,
                                  D_param, gamma, beta, wout,
                                  inWb, OWb, xpwb, t1b, x2sb, x1cb, urawb, zb,
                                  usb, deltab, Bm, Cm, cA, cB, AgA, AgB, gcar,
                                  out, bar);
}

// Round 6
// 257.972 us; speedup vs baseline: 2.5998x; 2.5998x over previous
//
#include <hip/hip_runtime.h>
#include <math.h>

#define B_    8
#define C_    128
#define D_    128
#define L_    4096
#define NPOS_ 32768
#define NC_   256          // scan chunks per batch
#define S_    16           // chunk length
#define MFL_  1048576

typedef __attribute__((ext_vector_type(8))) short short8;
typedef __attribute__((ext_vector_type(4))) float f32x4;

__device__ __forceinline__ float siluf(float x) { return x / (1.f + __expf(-x)); }
__device__ __forceinline__ float softplusf(float x) {
    if (x > 20.f) return x;
    return __logf(1.f + __expf(x));
}
__device__ __forceinline__ unsigned short f2bf(float f) {
    unsigned int u = __float_as_uint(f);
    u = (u + 0x7FFFu + ((u >> 16) & 1u)) >> 16;
    return (unsigned short)u;
}
__device__ __forceinline__ float bf2f(unsigned short h) {
    return __uint_as_float(((unsigned int)h) << 16);
}
__device__ __forceinline__ void scan_as(float dl, const float* Ar, bool fast, float* a) {
    if (fast) {
        float e1 = __expf(-dl);
        a[0] = e1;
        a[1] = e1 * e1;
        a[2] = a[1] * e1;
        a[3] = a[1] * a[1];
        a[4] = a[3] * e1;
        a[5] = a[3] * a[1];
        a[6] = a[5] * e1;
        a[7] = a[3] * a[3];
    } else {
        #pragma unroll
        for (int n = 0; n < 8; ++n) a[n] = __expf(dl * Ar[n]);
    }
}

// ---- K1: weight cvt (folded k0) + grouped 1x1. 32 pos/block, grid 1024 ----
// (round-2 form: 1 output/thread, 64 weight VGPRs -> higher occupancy)
__global__ __launch_bounds__(256) void k1_g1x1(const float* __restrict__ x,
                                               const float* __restrict__ w1,
                                               const float* __restrict__ w2,
                                               const float* __restrict__ inW,
                                               const float* __restrict__ OW,
                                               const float* __restrict__ xpw,
                                               unsigned short* __restrict__ inWb,
                                               unsigned short* __restrict__ OWb,
                                               unsigned short* __restrict__ xpwb,
                                               unsigned short* __restrict__ t1b,
                                               unsigned short* __restrict__ x2sb) {
    __shared__ float xs[16 * 128];
    int t = threadIdx.x;
    {
        int i = blockIdx.x * 51 + t;
        if (t < 51 && i < 52224) {
            if (i < 32768)      inWb[i] = f2bf(inW[i]);
            else if (i < 49152) OWb[i - 32768] = f2bf(OW[i - 32768]);
            else                xpwb[i - 49152] = f2bf(xpw[i - 49152]);
        }
    }
    int d = t & 127, ph = t >> 7;
    int g = d >> 5, o = d & 31;
    float w1r[32], w2r[32];
    #pragma unroll
    for (int i = 0; i < 32; ++i) {
        w1r[i] = w1[g * 1024 + o * 32 + i];
        w2r[i] = w2[g * 1024 + o * 32 + i];
    }
    int pos0 = blockIdx.x * 32;
    for (int it = 0; it < 2; ++it) {
        int p0 = pos0 + it * 16;
        #pragma unroll
        for (int q = 0; q < 2; ++q) {
            int fi = t * 2 + q;
            *(float4*)&xs[fi * 4] = *(const float4*)&x[p0 * 128 + fi * 4];
        }
        __syncthreads();
        #pragma unroll
        for (int q = 0; q < 8; ++q) {
            int pl = ph * 8 + q;
            float a1 = 0.f, a2 = 0.f;
            const float* xr = &xs[pl * 128 + g * 32];
            #pragma unroll
            for (int i4 = 0; i4 < 8; ++i4) {
                float4 xv = *(const float4*)&xr[i4 * 4];
                a1 += xv.x * w1r[i4*4] + xv.y * w1r[i4*4+1] + xv.z * w1r[i4*4+2] + xv.w * w1r[i4*4+3];
                a2 += xv.x * w2r[i4*4] + xv.y * w2r[i4*4+1] + xv.z * w2r[i4*4+2] + xv.w * w2r[i4*4+3];
            }
            int pos = p0 + pl;
            t1b[pos * 128 + d]  = f2bf(a1);
            x2sb[pos * 128 + d] = f2bf(siluf(a2));
        }
        __syncthreads();
    }
}

// ---- K2: depthwise 3x3 SAME + silu. bf16 in/out. 8x4 tile, grid 1024 ----
__global__ __launch_bounds__(128) void k2_dwconv(const unsigned short* __restrict__ t1b,
                                                 const float* __restrict__ dw,
                                                 unsigned short* __restrict__ x1cb) {
    int d = threadIdx.x;
    float dwr[9];
    #pragma unroll
    for (int k = 0; k < 9; ++k) dwr[k] = dw[k * 128 + d];
    int bid = blockIdx.x;             // 1024 = b(8) * ht(8) * wt(16)
    int wt = bid & 15, ht = (bid >> 4) & 7, b = bid >> 7;
    int h0 = ht * 8, w0 = wt * 4;
    float rows[10][6];
    #pragma unroll
    for (int r = 0; r < 10; ++r) {
        int hh = h0 - 1 + r;
        bool hv = (hh >= 0) && (hh < 64);
        #pragma unroll
        for (int c = 0; c < 6; ++c) {
            int w = w0 - 1 + c;
            bool wvv = (w >= 0) && (w < 64);
            rows[r][c] = (hv && wvv) ? bf2f(t1b[((b * 64 + hh) * 64 + w) * 128 + d]) : 0.f;
        }
    }
    #pragma unroll
    for (int hi = 0; hi < 8; ++hi) {
        #pragma unroll
        for (int wi = 0; wi < 4; ++wi) {
            float acc = rows[hi][wi]     * dwr[0] + rows[hi][wi+1]   * dwr[1] + rows[hi][wi+2]   * dwr[2]
                      + rows[hi+1][wi]   * dwr[3] + rows[hi+1][wi+1] * dwr[4] + rows[hi+1][wi+2] * dwr[5]
                      + rows[hi+2][wi]   * dwr[6] + rows[hi+2][wi+1] * dwr[7] + rows[hi+2][wi+2] * dwr[8];
            x1cb[((b * 64 + h0 + hi) * 64 + w0 + wi) * 128 + d] = f2bf(siluf(acc));
        }
    }
}

// ---- K3: in_proj via bf16 MFMA, 64-row m-tiles, both halves. grid 1024 ----
__global__ __launch_bounds__(256) void k3_mfma(const unsigned short* __restrict__ Abf,
                                               const unsigned short* __restrict__ Bbf,
                                               unsigned short* __restrict__ urawb,
                                               unsigned short* __restrict__ zb) {
    __shared__ unsigned short Al[64 * 72];
    __shared__ unsigned short Bl[128 * 72];
    int t = threadIdx.x;
    int pos0 = (blockIdx.x >> 1) * 64;
    int half = blockIdx.x & 1;
    const unsigned short* Bh = Bbf + (size_t)half * 128 * 128;
    unsigned short* dst = half ? zb : urawb;
    int lane = t & 63, wv = t >> 6;
    int lanem = lane & 15, laneq = lane >> 4;
    f32x4 acc[8];
    #pragma unroll
    for (int i = 0; i < 8; ++i) acc[i] = (f32x4){0.f, 0.f, 0.f, 0.f};
    for (int kc = 0; kc < 2; ++kc) {
        #pragma unroll
        for (int q = 0; q < 2; ++q) {
            int c = t + q * 256;
            int row = c >> 3, col = c & 7;
            *(int4*)&Al[row * 72 + col * 8] = *(const int4*)&Abf[(pos0 + row) * 128 + kc * 64 + col * 8];
        }
        #pragma unroll
        for (int q = 0; q < 4; ++q) {
            int c = t + q * 256;
            int row = c >> 3, col = c & 7;
            *(int4*)&Bl[row * 72 + col * 8] = *(const int4*)&Bh[row * 128 + kc * 64 + col * 8];
        }
        __syncthreads();
        #pragma unroll
        for (int ks = 0; ks < 2; ++ks) {
            short8 af = *(const short8*)&Al[(wv * 16 + lanem) * 72 + ks * 32 + laneq * 8];
            #pragma unroll
            for (int ni = 0; ni < 8; ++ni) {
                short8 bfr = *(const short8*)&Bl[(ni * 16 + lanem) * 72 + ks * 32 + laneq * 8];
                acc[ni] = __builtin_amdgcn_mfma_f32_16x16x32_bf16(af, bfr, acc[ni], 0, 0, 0);
            }
        }
        __syncthreads();
    }
    #pragma unroll
    for (int ni = 0; ni < 8; ++ni)
        #pragma unroll
        for (int r = 0; r < 4; ++r) {
            int m = pos0 + wv * 16 + laneq * 4 + r;
            int n = ni * 16 + lanem;
            dst[m * 128 + n] = f2bf(acc[ni][r]);
        }
}

// ---- K45: conv1d+silu -> usb ; x_proj MFMA ; delta bf16 ; Bm/Cm ; scan phase 1 ----
__global__ __launch_bounds__(256) void k45_convproj(const unsigned short* __restrict__ urawb,
                                                    const float* __restrict__ cw,
                                                    const float* __restrict__ cb,
                                                    const unsigned short* __restrict__ xpwb,
                                                    const float* __restrict__ dtw,
                                                    const float* __restrict__ dtb,
                                                    const float* __restrict__ A_log,
                                                    unsigned short* __restrict__ usb,
                                                    unsigned short* __restrict__ deltab,
                                                    float* __restrict__ Bm,
                                                    float* __restrict__ Cm,
                                                    float* __restrict__ cA,
                                                    float* __restrict__ cB) {
    __shared__ unsigned short uA[32 * 136];
    __shared__ unsigned short xB[32 * 136];
    __shared__ float xdb[32 * 36];
    int t = threadIdx.x;
    int d = t & 127, ph = t >> 7;
    for (int i = t; i < 32 * 128; i += 256) {
        int n = i >> 7, k = i & 127;
        xB[n * 136 + k] = (n < 24) ? xpwb[n * 128 + k] : (unsigned short)0;
    }
    float cw0 = cw[d * 3 + 0], cw1 = cw[d * 3 + 1], cw2 = cw[d * 3 + 2], cbr = cb[d];
    float dtwr[8];
    #pragma unroll
    for (int r = 0; r < 8; ++r) dtwr[r] = dtw[d * 8 + r];
    float dtbr = dtb[d];
    float Ar[8]; bool fast = true;
    #pragma unroll
    for (int n = 0; n < 8; ++n) {
        Ar[n] = -__expf(A_log[d * 8 + n]);
        fast = fast && (fabsf(Ar[n] + (float)(n + 1)) < 2e-3f);
    }

    int gpos0 = blockIdx.x * 32;
    int ll0 = (gpos0 & 4095) + ph * 16;
    int base = (gpos0 + ph * 16) * 128 + d;
    float ur0 = (ll0 >= 2) ? bf2f(urawb[base - 256]) : 0.f;
    float ur1 = (ll0 >= 1) ? bf2f(urawb[base - 128]) : 0.f;
    #pragma unroll
    for (int q = 0; q < 16; ++q) {
        float urq = bf2f(urawb[base + q * 128]);
        float v = siluf(ur0 * cw0 + ur1 * cw1 + urq * cw2 + cbr);
        unsigned short vb = f2bf(v);
        usb[base + q * 128] = vb;
        uA[(ph * 16 + q) * 136 + d] = vb;
        ur0 = ur1; ur1 = urq;
    }
    __syncthreads();
    int lane = t & 63, wv = t >> 6;
    int lanem = lane & 15, laneq = lane >> 4;
    int m0 = (wv & 1) * 16, n0 = (wv >> 1) * 16;
    f32x4 accx = (f32x4){0.f, 0.f, 0.f, 0.f};
    #pragma unroll
    for (int ks = 0; ks < 4; ++ks) {
        short8 af  = *(const short8*)&uA[(m0 + lanem) * 136 + ks * 32 + laneq * 8];
        short8 bfr = *(const short8*)&xB[(n0 + lanem) * 136 + ks * 32 + laneq * 8];
        accx = __builtin_amdgcn_mfma_f32_16x16x32_bf16(af, bfr, accx, 0, 0, 0);
    }
    #pragma unroll
    for (int r = 0; r < 4; ++r)
        xdb[(m0 + laneq * 4 + r) * 36 + n0 + lanem] = accx[r];
    __syncthreads();
    // delta (bf16 store; scan uses the SAME bf16-rounded value so k7 replay matches)
    float h[8], ap[8];
    #pragma unroll
    for (int n = 0; n < 8; ++n) { h[n] = 0.f; ap[n] = 1.f; }
    #pragma unroll
    for (int q = 0; q < 16; ++q) {
        int pl = ph * 16 + q;
        const float* xrow = &xdb[pl * 36];
        float4 d0 = *(const float4*)&xrow[0];
        float4 d1 = *(const float4*)&xrow[4];
        float dt = dtbr + d0.x * dtwr[0] + d0.y * dtwr[1] + d0.z * dtwr[2] + d0.w * dtwr[3]
                        + d1.x * dtwr[4] + d1.y * dtwr[5] + d1.z * dtwr[6] + d1.w * dtwr[7];
        unsigned short dlb = f2bf(softplusf(dt));
        deltab[base + q * 128] = dlb;
        float dl = bf2f(dlb);
        float du = dl * bf2f(uA[pl * 136 + d]);
        float bmv[8];
        *(float4*)&bmv[0] = *(const float4*)&xrow[8];
        *(float4*)&bmv[4] = *(const float4*)&xrow[12];
        float a[8];
        scan_as(dl, Ar, fast, a);
        #pragma unroll
        for (int n = 0; n < 8; ++n) {
            ap[n] *= a[n];
            h[n] = a[n] * h[n] + du * bmv[n];
        }
    }
    int bH = gpos0 >> 12;
    int c  = ((gpos0 & 4095) >> 4) + ph;
    int obase = ((bH * NC_ + c) * 128 + d) * 8;
    *(float4*)&cA[obase]     = make_float4(ap[0], ap[1], ap[2], ap[3]);
    *(float4*)&cA[obase + 4] = make_float4(ap[4], ap[5], ap[6], ap[7]);
    *(float4*)&cB[obase]     = make_float4(h[0], h[1], h[2], h[3]);
    *(float4*)&cB[obase + 4] = make_float4(h[4], h[5], h[6], h[7]);
    if (t < 128) {
        int p = t >> 2, q = t & 3;
        float4 v = *(const float4*)&xdb[p * 36 + 8 + q * 4];
        int gp = gpos0 + p;
        if (q < 2) *(float4*)&Bm[gp * 8 + q * 4] = v;
        else       *(float4*)&Cm[gp * 8 + (q - 2) * 4] = v;
    }
}

// ---- K6a: scan phase 2a — in-place within-group (16 chunks) prefix + aggregates ----
__global__ __launch_bounds__(256) void k6a_scan(float* __restrict__ cA,
                                                float* __restrict__ cB,
                                                float* __restrict__ AgA,
                                                float* __restrict__ AgB) {
    int id = blockIdx.x * 256 + threadIdx.x;   // 131072 = 8b * 16grp * 1024dn
    int dn = id & 1023;
    int grp = (id >> 10) & 15;
    int b = id >> 14;
    float Apre = 1.f, h = 0.f;
    int base = (b * NC_ + grp * 16) * 1024 + dn;
    #pragma unroll 4
    for (int j = 0; j < 16; ++j) {
        int idx = base + j * 1024;
        float a  = cA[idx];
        float bv = cB[idx];
        cA[idx] = Apre;
        cB[idx] = h;
        Apre *= a;
        h = a * h + bv;
    }
    int aidx = (b * 16 + grp) * 1024 + dn;
    AgA[aidx] = Apre;
    AgB[aidx] = h;
}

// ---- K6b: scan phase 2b — serial scan over 16 group aggregates ----
__global__ __launch_bounds__(256) void k6b_scan(const float* __restrict__ AgA,
                                                const float* __restrict__ AgB,
                                                float* __restrict__ gcar) {
    int id = blockIdx.x * 256 + threadIdx.x;   // 8192 = 8b * 1024dn
    int dn = id & 1023;
    int b = id >> 10;
    float h = 0.f;
    #pragma unroll
    for (int grp = 0; grp < 16; ++grp) {
        int idx = (b * 16 + grp) * 1024 + dn;
        float Ag = AgA[idx];
        float Bg = AgB[idx];
        gcar[idx] = h;
        h = Ag * h + Bg;
    }
}

// ---- K7F: scan phase 3 + out_proj MFMA + LN + *x2s + wout, fused.
//      64 pos/block (4 chunks), grid 512 x 256.
//      LDS cut 57.4->37.9KB: wout/gamma/beta read direct from global (L1-resident,
//      bit-identical values). launch_bounds(256,3) for >=3 waves/SIMD. ----
__global__ __launch_bounds__(256, 3) void k7f_fused(const unsigned short* __restrict__ deltab,
                                                    const unsigned short* __restrict__ usb,
                                                    const float* __restrict__ Bm,
                                                    const float* __restrict__ Cm,
                                                    const unsigned short* __restrict__ zb,
                                                    const float* __restrict__ A_log,
                                                    const float* __restrict__ Dp,
                                                    const float* __restrict__ Apre,
                                                    const float* __restrict__ Bpre,
                                                    const float* __restrict__ gcar,
                                                    const unsigned short* __restrict__ OWb,
                                                    const float* __restrict__ gamma,
                                                    const float* __restrict__ beta,
                                                    const unsigned short* __restrict__ x2sb,
                                                    const float* __restrict__ wout,
                                                    float* __restrict__ out) {
    // yA [2][64][72] bf16 (0..18432B) + Bl [128][72] bf16 (18432..36864B);
    // xz [64][148] fp32 (0..37888B) reuses the same region after phase B.
    __shared__ __align__(16) char smem[37888];
    unsigned short* yA = (unsigned short*)smem;
    unsigned short* Bl = (unsigned short*)(smem + 18432);
    float* xz = (float*)smem;
    int t = threadIdx.x;

    // ---- phase A: per-chunk scan replay, y -> LDS bf16 ----
    int d = t & 127, ph = t >> 7;
    int b = blockIdx.x >> 6, cblk = blockIdx.x & 63;
    float Ar[8]; bool fast = true;
    #pragma unroll
    for (int n = 0; n < 8; ++n) {
        Ar[n] = -__expf(A_log[d * 8 + n]);
        fast = fast && (fabsf(Ar[n] + (float)(n + 1)) < 2e-3f);
    }
    float Dpr = Dp[d];
    int ybase = (d >> 6) * (64 * 72) + (d & 63);
    for (int cc = 0; cc < 2; ++cc) {
        int cl = ph * 2 + cc;
        int c = cblk * 4 + cl;
        int cbase = ((b * NC_ + c) * 128 + d) * 8;
        float4 ap0 = *(const float4*)&Apre[cbase];
        float4 ap1 = *(const float4*)&Apre[cbase + 4];
        float4 bp0 = *(const float4*)&Bpre[cbase];
        float4 bp1 = *(const float4*)&Bpre[cbase + 4];
        int gbase = (b * 16 + (c >> 4)) * 1024 + d * 8;
        float4 g0 = *(const float4*)&gcar[gbase];
        float4 g1 = *(const float4*)&gcar[gbase + 4];
        float h[8] = { fmaf(g0.x, ap0.x, bp0.x), fmaf(g0.y, ap0.y, bp0.y),
                       fmaf(g0.z, ap0.z, bp0.z), fmaf(g0.w, ap0.w, bp0.w),
                       fmaf(g1.x, ap1.x, bp1.x), fmaf(g1.y, ap1.y, bp1.y),
                       fmaf(g1.z, ap1.z, bp1.z), fmaf(g1.w, ap1.w, bp1.w) };
        int base  = (b * L_ + c * S_) * 128 + d;
        int bbase = (b * L_ + c * S_) * 8;
        #pragma unroll
        for (int s = 0; s < S_; ++s) {
            float dl = bf2f(deltab[base + s * 128]);
            float uv = bf2f(usb[base + s * 128]);
            float zv = bf2f(zb[base + s * 128]);
            float du = dl * uv;
            float4 bm0 = *(const float4*)&Bm[bbase + s * 8];
            float4 bm1 = *(const float4*)&Bm[bbase + s * 8 + 4];
            float4 cm0 = *(const float4*)&Cm[bbase + s * 8];
            float4 cm1 = *(const float4*)&Cm[bbase + s * 8 + 4];
            float a[8];
            scan_as(dl, Ar, fast, a);
            h[0] = a[0] * h[0] + du * bm0.x;
            h[1] = a[1] * h[1] + du * bm0.y;
            h[2] = a[2] * h[2] + du * bm0.z;
            h[3] = a[3] * h[3] + du * bm0.w;
            h[4] = a[4] * h[4] + du * bm1.x;
            h[5] = a[5] * h[5] + du * bm1.y;
            h[6] = a[6] * h[6] + du * bm1.z;
            h[7] = a[7] * h[7] + du * bm1.w;
            float yv = h[0] * cm0.x + h[1] * cm0.y + h[2] * cm0.z + h[3] * cm0.w
                     + h[4] * cm1.x + h[5] * cm1.y + h[6] * cm1.z + h[7] * cm1.w;
            yv = (yv + uv * Dpr) * siluf(zv);
            yA[ybase + (cl * 16 + s) * 72] = f2bf(yv);
        }
    }
    __syncthreads();

    // ---- phase B: out_proj MFMA (old K8a loop verbatim; A from LDS) ----
    int lane = t & 63, wv = t >> 6;
    int lanem = lane & 15, laneq = lane >> 4;
    f32x4 acc[8];
    #pragma unroll
    for (int i = 0; i < 8; ++i) acc[i] = (f32x4){0.f, 0.f, 0.f, 0.f};
    for (int kc = 0; kc < 2; ++kc) {
        #pragma unroll
        for (int q = 0; q < 4; ++q) {
            int cidx = t + q * 256;
            int row = cidx >> 3, col = cidx & 7;
            *(int4*)&Bl[row * 72 + col * 8] = *(const int4*)&OWb[row * 128 + kc * 64 + col * 8];
        }
        __syncthreads();
        #pragma unroll
        for (int ks = 0; ks < 2; ++ks) {
            short8 af = *(const short8*)&yA[kc * (64 * 72) + (wv * 16 + lanem) * 72 + ks * 32 + laneq * 8];
            #pragma unroll
            for (int ni = 0; ni < 8; ++ni) {
                short8 bfr = *(const short8*)&Bl[(ni * 16 + lanem) * 72 + ks * 32 + laneq * 8];
                acc[ni] = __builtin_amdgcn_mfma_f32_16x16x32_bf16(af, bfr, acc[ni], 0, 0, 0);
            }
        }
        __syncthreads();   // last iteration: also guards xz overwrite of yA/Bl
    }
    // acc -> xz, rounded through bf16 exactly like old xzb. Skewed cols:
    // col = ch + (ch>>5)*4, row stride 148.
    #pragma unroll
    for (int ni = 0; ni < 8; ++ni) {
        int ch = ni * 16 + lanem;
        int col = ch + ((ch >> 5) << 2);
        #pragma unroll
        for (int r = 0; r < 4; ++r)
            xz[(wv * 16 + laneq * 4 + r) * 148 + col] = bf2f(f2bf(acc[ni][r]));
    }
    __syncthreads();

    // ---- phase C: LayerNorm + *silu(x2) (4 thr/row, 32 ch each; gamma/beta from global) ----
    int g = t & 3, pos = t >> 2;
    int gpos = b * L_ + cblk * 64 + pos;
    const float* xrow0 = &xz[pos * 148 + g * 36];
    float v[32];
    #pragma unroll
    for (int i4 = 0; i4 < 8; ++i4) {
        float4 xv = *(const float4*)&xrow0[i4 * 4];
        v[i4*4+0] = xv.x; v[i4*4+1] = xv.y;
        v[i4*4+2] = xv.z; v[i4*4+3] = xv.w;
    }
    float s = 0.f, s2 = 0.f;
    #pragma unroll
    for (int i = 0; i < 32; ++i) { s += v[i]; s2 += v[i] * v[i]; }
    s  += __shfl_xor(s, 1, 64);  s  += __shfl_xor(s, 2, 64);
    s2 += __shfl_xor(s2, 1, 64); s2 += __shfl_xor(s2, 2, 64);
    float m = s * (1.f / 128.f);
    float var = s2 * (1.f / 128.f) - m * m;
    float rstd = rsqrtf(var + 1e-5f);
    #pragma unroll
    for (int i4 = 0; i4 < 8; ++i4) {
        ushort4 xv = *(const ushort4*)&x2sb[gpos * 128 + g * 32 + i4 * 4];
        unsigned short xa[4] = {xv.x, xv.y, xv.z, xv.w};
        float4 g4 = *(const float4*)&gamma[g * 32 + i4 * 4];
        float4 b4 = *(const float4*)&beta[g * 32 + i4 * 4];
        float ga[4] = {g4.x, g4.y, g4.z, g4.w};
        float be[4] = {b4.x, b4.y, b4.z, b4.w};
        #pragma unroll
        for (int k = 0; k < 4; ++k) {
            float vv = (v[i4 * 4 + k] - m) * rstd * ga[k] + be[k];
            v[i4 * 4 + k] = vv * bf2f(xa[k]);
        }
    }

    // ---- phase D: grouped wout (register-resident v; weights from global/L1) ----
    const float* wg = &wout[g * 1024];
    int obase = gpos * 128 + g * 32;
    #pragma unroll
    for (int ob = 0; ob < 8; ++ob) {
        float o4[4];
        #pragma unroll
        for (int oo = 0; oo < 4; ++oo) {
            int o = ob * 4 + oo;
            float acc2 = 0.f;
            #pragma unroll
            for (int i4 = 0; i4 < 8; ++i4) {
                float4 wv4 = *(const float4*)&wg[o * 32 + i4 * 4];
                acc2 += v[i4*4] * wv4.x + v[i4*4+1] * wv4.y
                      + v[i4*4+2] * wv4.z + v[i4*4+3] * wv4.w;
            }
            o4[oo] = acc2;
        }
        *(float4*)&out[obase + ob * 4] = make_float4(o4[0], o4[1], o4[2], o4[3]);
    }
}

extern "C" void kernel_launch(void* const* d_in, const int* in_sizes, int n_in,
                              void* d_out, int out_size, void* d_ws, size_t ws_size,
                              hipStream_t stream) {
    (void)in_sizes; (void)n_in; (void)out_size; (void)ws_size;
    const float* x         = (const float*)d_in[0];
    const float* w1        = (const float*)d_in[1];
    const float* dw        = (const float*)d_in[2];
    const float* in_proj_w = (const float*)d_in[3];
    const float* conv1d_w  = (const float*)d_in[4];
    const float* conv1d_b  = (const float*)d_in[5];
    const float* x_proj_w  = (const float*)d_in[6];
    const float* dt_proj_w = (const float*)d_in[7];
    const float* dt_proj_b = (const float*)d_in[8];
    const float* A_log     = (const float*)d_in[9];
    const float* D_param   = (const float*)d_in[10];
    const float* out_proj_w= (const float*)d_in[11];
    const float* gamma     = (const float*)d_in[12];
    const float* beta      = (const float*)d_in[13];
    const float* w2        = (const float*)d_in[14];
    const float* wout      = (const float*)d_in[15];
    float* out = (float*)d_out;

    float* ws = (float*)d_ws;
    unsigned short* x2sb   = (unsigned short*)(ws);
    unsigned short* t1b    = (unsigned short*)(ws + 2  * (size_t)MFL_);
    unsigned short* x1cb   = (unsigned short*)(ws + 4  * (size_t)MFL_);
    unsigned short* urawb  = (unsigned short*)(ws + 6  * (size_t)MFL_);
    unsigned short* zb     = (unsigned short*)(ws + 8  * (size_t)MFL_);
    unsigned short* usb    = (unsigned short*)(ws + 14 * (size_t)MFL_);
    unsigned short* deltab = (unsigned short*)(ws + 16 * (size_t)MFL_);
    float* Bm    = ws + 18 * (size_t)MFL_;            // 262144
    float* Cm    = Bm + (size_t)NPOS_ * 8;            // 262144
    float* cA    = Cm + (size_t)NPOS_ * 8;            // 2M fl
    float* cB    = cA + 2 * (size_t)MFL_;             // 2M fl
    float* scanw = cB + 2 * (size_t)MFL_;             // reuse old carry region
    float* AgA   = scanw;                             // 131072 fl
    float* AgB   = scanw + 131072;                    // 131072 fl
    float* gcar  = scanw + 262144;                    // 131072 fl
    unsigned short* inWb = (unsigned short*)(scanw + 2 * (size_t)MFL_);
    unsigned short* OWb  = inWb + 32768;
    unsigned short* xpwb = OWb + 16384;

    k1_g1x1<<<1024, 256, 0, stream>>>(x, w1, w2, in_proj_w, out_proj_w, x_proj_w,
                                      inWb, OWb, xpwb, t1b, x2sb);
    k2_dwconv<<<1024, 128, 0, stream>>>(t1b, dw, x1cb);
    k3_mfma<<<1024, 256, 0, stream>>>(x1cb, inWb, urawb, zb);
    k45_convproj<<<1024, 256, 0, stream>>>(urawb, conv1d_w, conv1d_b, xpwb,
                                           dt_proj_w, dt_proj_b, A_log,
                                           usb, deltab, Bm, Cm, cA, cB);
    k6a_scan<<<512, 256, 0, stream>>>(cA, cB, AgA, AgB);
    k6b_scan<<<32, 256, 0, stream>>>(AgA, AgB, gcar);
    k7f_fused<<<512, 256, 0, stream>>>(deltab, usb, Bm, Cm, zb, A_log, D_param,
                                       cA, cB, gcar, OWb, gamma, beta, x2sb, wout, out);
}

// Round 8
// 212.673 us; speedup vs baseline: 3.1535x; 1.2130x over previous
//
#include <hip/hip_runtime.h>
#include <math.h>

#define B_    8
#define C_    128
#define D_    128
#define L_    4096
#define NPOS_ 32768
#define NC_   256          // scan chunks per batch
#define S_    16           // chunk length
#define MFL_  1048576

typedef __attribute__((ext_vector_type(8))) short short8;
typedef __attribute__((ext_vector_type(4))) float f32x4;

__device__ __forceinline__ float siluf(float x) { return x / (1.f + __expf(-x)); }
__device__ __forceinline__ float softplusf(float x) {
    if (x > 20.f) return x;
    return __logf(1.f + __expf(x));
}
__device__ __forceinline__ unsigned short f2bf(float f) {
    unsigned int u = __float_as_uint(f);
    u = (u + 0x7FFFu + ((u >> 16) & 1u)) >> 16;
    return (unsigned short)u;
}
__device__ __forceinline__ float bf2f(unsigned short h) {
    return __uint_as_float(((unsigned int)h) << 16);
}
__device__ __forceinline__ void scan_as(float dl, const float* Ar, bool fast, float* a) {
    if (fast) {
        float e1 = __expf(-dl);
        a[0] = e1;
        a[1] = e1 * e1;
        a[2] = a[1] * e1;
        a[3] = a[1] * a[1];
        a[4] = a[3] * e1;
        a[5] = a[3] * a[1];
        a[6] = a[5] * e1;
        a[7] = a[3] * a[3];
    } else {
        #pragma unroll
        for (int n = 0; n < 8; ++n) a[n] = __expf(dl * Ar[n]);
    }
}

// ---- K1: weight cvt (folded k0) + grouped 1x1, 2 outputs/thread. 32 pos/block ----
__global__ __launch_bounds__(256) void k1_g1x1(const float* __restrict__ x,
                                               const float* __restrict__ w1,
                                               const float* __restrict__ w2,
                                               const float* __restrict__ inW,
                                               const float* __restrict__ OW,
                                               const float* __restrict__ xpw,
                                               unsigned short* __restrict__ inWb,
                                               unsigned short* __restrict__ OWb,
                                               unsigned short* __restrict__ xpwb,
                                               unsigned short* __restrict__ t1b,
                                               unsigned short* __restrict__ x2sb) {
    __shared__ float xs[16 * 128];
    int t = threadIdx.x;
    {
        int i = blockIdx.x * 51 + t;
        if (t < 51 && i < 52224) {
            if (i < 32768)      inWb[i] = f2bf(inW[i]);
            else if (i < 49152) OWb[i - 32768] = f2bf(OW[i - 32768]);
            else                xpwb[i - 49152] = f2bf(xpw[i - 49152]);
        }
    }
    int op = t & 63, ph = t >> 6;
    int g = op >> 4, o2 = (op & 15) * 2;
    const float* w1p = &w1[g * 1024 + o2 * 32];
    const float* w2p = &w2[g * 1024 + o2 * 32];
    float w1r[64], w2r[64];
    #pragma unroll
    for (int i = 0; i < 64; ++i) { w1r[i] = w1p[i]; w2r[i] = w2p[i]; }
    int pos0 = blockIdx.x * 32;
    for (int it = 0; it < 2; ++it) {
        int p0 = pos0 + it * 16;
        #pragma unroll
        for (int q = 0; q < 2; ++q) {
            int fi = t * 2 + q;
            *(float4*)&xs[fi * 4] = *(const float4*)&x[p0 * 128 + fi * 4];
        }
        __syncthreads();
        #pragma unroll
        for (int q = 0; q < 4; ++q) {
            int pl = ph * 4 + q;
            float a1 = 0.f, b1 = 0.f, a2 = 0.f, b2 = 0.f;
            const float* xr = &xs[pl * 128 + g * 32];
            #pragma unroll
            for (int i4 = 0; i4 < 8; ++i4) {
                float4 xv = *(const float4*)&xr[i4 * 4];
                a1 += xv.x * w1r[i4*4]    + xv.y * w1r[i4*4+1]    + xv.z * w1r[i4*4+2]    + xv.w * w1r[i4*4+3];
                b1 += xv.x * w1r[32+i4*4] + xv.y * w1r[32+i4*4+1] + xv.z * w1r[32+i4*4+2] + xv.w * w1r[32+i4*4+3];
                a2 += xv.x * w2r[i4*4]    + xv.y * w2r[i4*4+1]    + xv.z * w2r[i4*4+2]    + xv.w * w2r[i4*4+3];
                b2 += xv.x * w2r[32+i4*4] + xv.y * w2r[32+i4*4+1] + xv.z * w2r[32+i4*4+2] + xv.w * w2r[32+i4*4+3];
            }
            int pos = p0 + pl;
            int db = pos * 128 + g * 32 + o2;
            unsigned int u1 = (unsigned int)f2bf(a1) | ((unsigned int)f2bf(b1) << 16);
            unsigned int u2 = (unsigned int)f2bf(siluf(a2)) | ((unsigned int)f2bf(siluf(b2)) << 16);
            *(unsigned int*)&t1b[db]  = u1;
            *(unsigned int*)&x2sb[db] = u2;
        }
        __syncthreads();
    }
}

// ---- K2: depthwise 3x3 SAME + silu. bf16 in/out. 8x4 tile, grid 1024 ----
__global__ __launch_bounds__(128) void k2_dwconv(const unsigned short* __restrict__ t1b,
                                                 const float* __restrict__ dw,
                                                 unsigned short* __restrict__ x1cb) {
    int d = threadIdx.x;
    float dwr[9];
    #pragma unroll
    for (int k = 0; k < 9; ++k) dwr[k] = dw[k * 128 + d];
    int bid = blockIdx.x;             // 1024 = b(8) * ht(8) * wt(16)
    int wt = bid & 15, ht = (bid >> 4) & 7, b = bid >> 7;
    int h0 = ht * 8, w0 = wt * 4;
    float rows[10][6];
    #pragma unroll
    for (int r = 0; r < 10; ++r) {
        int hh = h0 - 1 + r;
        bool hv = (hh >= 0) && (hh < 64);
        #pragma unroll
        for (int c = 0; c < 6; ++c) {
            int w = w0 - 1 + c;
            bool wvv = (w >= 0) && (w < 64);
            rows[r][c] = (hv && wvv) ? bf2f(t1b[((b * 64 + hh) * 64 + w) * 128 + d]) : 0.f;
        }
    }
    #pragma unroll
    for (int hi = 0; hi < 8; ++hi) {
        #pragma unroll
        for (int wi = 0; wi < 4; ++wi) {
            float acc = rows[hi][wi]     * dwr[0] + rows[hi][wi+1]   * dwr[1] + rows[hi][wi+2]   * dwr[2]
                      + rows[hi+1][wi]   * dwr[3] + rows[hi+1][wi+1] * dwr[4] + rows[hi+1][wi+2] * dwr[5]
                      + rows[hi+2][wi]   * dwr[6] + rows[hi+2][wi+1] * dwr[7] + rows[hi+2][wi+2] * dwr[8];
            x1cb[((b * 64 + h0 + hi) * 64 + w0 + wi) * 128 + d] = f2bf(siluf(acc));
        }
    }
}

// ---- K3: in_proj via bf16 MFMA, 64-row m-tiles, both halves. grid 1024 ----
__global__ __launch_bounds__(256) void k3_mfma(const unsigned short* __restrict__ Abf,
                                               const unsigned short* __restrict__ Bbf,
                                               unsigned short* __restrict__ urawb,
                                               unsigned short* __restrict__ zb) {
    __shared__ unsigned short Al[64 * 72];
    __shared__ unsigned short Bl[128 * 72];
    int t = threadIdx.x;
    int pos0 = (blockIdx.x >> 1) * 64;
    int half = blockIdx.x & 1;
    const unsigned short* Bh = Bbf + (size_t)half * 128 * 128;
    unsigned short* dst = half ? zb : urawb;
    int lane = t & 63, wv = t >> 6;
    int lanem = lane & 15, laneq = lane >> 4;
    f32x4 acc[8];
    #pragma unroll
    for (int i = 0; i < 8; ++i) acc[i] = (f32x4){0.f, 0.f, 0.f, 0.f};
    for (int kc = 0; kc < 2; ++kc) {
        #pragma unroll
        for (int q = 0; q < 2; ++q) {
            int c = t + q * 256;
            int row = c >> 3, col = c & 7;
            *(int4*)&Al[row * 72 + col * 8] = *(const int4*)&Abf[(pos0 + row) * 128 + kc * 64 + col * 8];
        }
        #pragma unroll
        for (int q = 0; q < 4; ++q) {
            int c = t + q * 256;
            int row = c >> 3, col = c & 7;
            *(int4*)&Bl[row * 72 + col * 8] = *(const int4*)&Bh[row * 128 + kc * 64 + col * 8];
        }
        __syncthreads();
        #pragma unroll
        for (int ks = 0; ks < 2; ++ks) {
            short8 af = *(const short8*)&Al[(wv * 16 + lanem) * 72 + ks * 32 + laneq * 8];
            #pragma unroll
            for (int ni = 0; ni < 8; ++ni) {
                short8 bfr = *(const short8*)&Bl[(ni * 16 + lanem) * 72 + ks * 32 + laneq * 8];
                acc[ni] = __builtin_amdgcn_mfma_f32_16x16x32_bf16(af, bfr, acc[ni], 0, 0, 0);
            }
        }
        __syncthreads();
    }
    #pragma unroll
    for (int ni = 0; ni < 8; ++ni)
        #pragma unroll
        for (int r = 0; r < 4; ++r) {
            int m = pos0 + wv * 16 + laneq * 4 + r;
            int n = ni * 16 + lanem;
            dst[m * 128 + n] = f2bf(acc[ni][r]);
        }
}

// ---- K45: conv1d+silu -> usb ; x_proj MFMA ; delta bf16 ; Bm/Cm ; scan phase 1 ----
__global__ __launch_bounds__(256) void k45_convproj(const unsigned short* __restrict__ urawb,
                                                    const float* __restrict__ cw,
                                                    const float* __restrict__ cb,
                                                    const unsigned short* __restrict__ xpwb,
                                                    const float* __restrict__ dtw,
                                                    const float* __restrict__ dtb,
                                                    const float* __restrict__ A_log,
                                                    unsigned short* __restrict__ usb,
                                                    unsigned short* __restrict__ deltab,
                                                    float* __restrict__ Bm,
                                                    float* __restrict__ Cm,
                                                    float* __restrict__ cA,
                                                    float* __restrict__ cB) {
    __shared__ unsigned short uA[32 * 136];
    __shared__ unsigned short xB[32 * 136];
    __shared__ float xdb[32 * 36];
    int t = threadIdx.x;
    int d = t & 127, ph = t >> 7;
    for (int i = t; i < 32 * 128; i += 256) {
        int n = i >> 7, k = i & 127;
        xB[n * 136 + k] = (n < 24) ? xpwb[n * 128 + k] : (unsigned short)0;
    }
    float cw0 = cw[d * 3 + 0], cw1 = cw[d * 3 + 1], cw2 = cw[d * 3 + 2], cbr = cb[d];
    float dtwr[8];
    #pragma unroll
    for (int r = 0; r < 8; ++r) dtwr[r] = dtw[d * 8 + r];
    float dtbr = dtb[d];
    float Ar[8]; bool fast = true;
    #pragma unroll
    for (int n = 0; n < 8; ++n) {
        Ar[n] = -__expf(A_log[d * 8 + n]);
        fast = fast && (fabsf(Ar[n] + (float)(n + 1)) < 2e-3f);
    }

    int gpos0 = blockIdx.x * 32;
    int ll0 = (gpos0 & 4095) + ph * 16;
    int base = (gpos0 + ph * 16) * 128 + d;
    float ur0 = (ll0 >= 2) ? bf2f(urawb[base - 256]) : 0.f;
    float ur1 = (ll0 >= 1) ? bf2f(urawb[base - 128]) : 0.f;
    #pragma unroll
    for (int q = 0; q < 16; ++q) {
        float urq = bf2f(urawb[base + q * 128]);
        float v = siluf(ur0 * cw0 + ur1 * cw1 + urq * cw2 + cbr);
        unsigned short vb = f2bf(v);
        usb[base + q * 128] = vb;
        uA[(ph * 16 + q) * 136 + d] = vb;
        ur0 = ur1; ur1 = urq;
    }
    __syncthreads();
    int lane = t & 63, wv = t >> 6;
    int lanem = lane & 15, laneq = lane >> 4;
    int m0 = (wv & 1) * 16, n0 = (wv >> 1) * 16;
    f32x4 accx = (f32x4){0.f, 0.f, 0.f, 0.f};
    #pragma unroll
    for (int ks = 0; ks < 4; ++ks) {
        short8 af  = *(const short8*)&uA[(m0 + lanem) * 136 + ks * 32 + laneq * 8];
        short8 bfr = *(const short8*)&xB[(n0 + lanem) * 136 + ks * 32 + laneq * 8];
        accx = __builtin_amdgcn_mfma_f32_16x16x32_bf16(af, bfr, accx, 0, 0, 0);
    }
    #pragma unroll
    for (int r = 0; r < 4; ++r)
        xdb[(m0 + laneq * 4 + r) * 36 + n0 + lanem] = accx[r];
    __syncthreads();
    // delta (bf16 store; scan uses the SAME bf16-rounded value so k7 replay matches)
    float h[8], ap[8];
    #pragma unroll
    for (int n = 0; n < 8; ++n) { h[n] = 0.f; ap[n] = 1.f; }
    #pragma unroll
    for (int q = 0; q < 16; ++q) {
        int pl = ph * 16 + q;
        const float* xrow = &xdb[pl * 36];
        float4 d0 = *(const float4*)&xrow[0];
        float4 d1 = *(const float4*)&xrow[4];
        float dt = dtbr + d0.x * dtwr[0] + d0.y * dtwr[1] + d0.z * dtwr[2] + d0.w * dtwr[3]
                        + d1.x * dtwr[4] + d1.y * dtwr[5] + d1.z * dtwr[6] + d1.w * dtwr[7];
        unsigned short dlb = f2bf(softplusf(dt));
        deltab[base + q * 128] = dlb;
        float dl = bf2f(dlb);
        float du = dl * bf2f(uA[pl * 136 + d]);
        float bmv[8];
        *(float4*)&bmv[0] = *(const float4*)&xrow[8];
        *(float4*)&bmv[4] = *(const float4*)&xrow[12];
        float a[8];
        scan_as(dl, Ar, fast, a);
        #pragma unroll
        for (int n = 0; n < 8; ++n) {
            ap[n] *= a[n];
            h[n] = a[n] * h[n] + du * bmv[n];
        }
    }
    int bH = gpos0 >> 12;
    int c  = ((gpos0 & 4095) >> 4) + ph;
    int obase = ((bH * NC_ + c) * 128 + d) * 8;
    *(float4*)&cA[obase]     = make_float4(ap[0], ap[1], ap[2], ap[3]);
    *(float4*)&cA[obase + 4] = make_float4(ap[4], ap[5], ap[6], ap[7]);
    *(float4*)&cB[obase]     = make_float4(h[0], h[1], h[2], h[3]);
    *(float4*)&cB[obase + 4] = make_float4(h[4], h[5], h[6], h[7]);
    if (t < 128) {
        int p = t >> 2, q = t & 3;
        float4 v = *(const float4*)&xdb[p * 36 + 8 + q * 4];
        int gp = gpos0 + p;
        if (q < 2) *(float4*)&Bm[gp * 8 + q * 4] = v;
        else       *(float4*)&Cm[gp * 8 + (q - 2) * 4] = v;
    }
}

// ---- K6a: scan phase 2a — in-place within-group (16 chunks) prefix + aggregates ----
__global__ __launch_bounds__(256) void k6a_scan(float* __restrict__ cA,
                                                float* __restrict__ cB,
                                                float* __restrict__ AgA,
                                                float* __restrict__ AgB) {
    int id = blockIdx.x * 256 + threadIdx.x;   // 131072 = 8b * 16grp * 1024dn
    int dn = id & 1023;
    int grp = (id >> 10) & 15;
    int b = id >> 14;
    float Apre = 1.f, h = 0.f;
    int base = (b * NC_ + grp * 16) * 1024 + dn;
    #pragma unroll 4
    for (int j = 0; j < 16; ++j) {
        int idx = base + j * 1024;
        float a  = cA[idx];
        float bv = cB[idx];
        cA[idx] = Apre;
        cB[idx] = h;
        Apre *= a;
        h = a * h + bv;
    }
    int aidx = (b * 16 + grp) * 1024 + dn;
    AgA[aidx] = Apre;
    AgB[aidx] = h;
}

// ---- K6b: scan phase 2b — serial scan over 16 group aggregates ----
__global__ __launch_bounds__(256) void k6b_scan(const float* __restrict__ AgA,
                                                const float* __restrict__ AgB,
                                                float* __restrict__ gcar) {
    int id = blockIdx.x * 256 + threadIdx.x;   // 8192 = 8b * 1024dn
    int dn = id & 1023;
    int b = id >> 10;
    float h = 0.f;
    #pragma unroll
    for (int grp = 0; grp < 16; ++grp) {
        int idx = (b * 16 + grp) * 1024 + dn;
        float Ag = AgA[idx];
        float Bg = AgB[idx];
        gcar[idx] = h;
        h = Ag * h + Bg;
    }
}

// ---- K7F: scan phase 3 + out_proj MFMA + LN + *x2s + wout, fused.
//      64 pos/block (4 chunks), grid 512 — SAME tile/LDS/chunk math as the
//      verified round-4 kernel, widened to 512 threads (8 waves):
//      phase A = 1 chunk per (d, ph in [0,4)); phase B = 8 waves x acc[4];
//      phases C+D = round-4 VERBATIM under t<256 (identical thread indices). ----
__global__ __launch_bounds__(512) void k7f_fused(const unsigned short* __restrict__ deltab,
                                                 const unsigned short* __restrict__ usb,
                                                 const float* __restrict__ Bm,
                                                 const float* __restrict__ Cm,
                                                 const unsigned short* __restrict__ zb,
                                                 const float* __restrict__ A_log,
                                                 const float* __restrict__ Dp,
                                                 const float* __restrict__ Apre,
                                                 const float* __restrict__ Bpre,
                                                 const float* __restrict__ gcar,
                                                 const unsigned short* __restrict__ OWb,
                                                 const float* __restrict__ gamma,
                                                 const float* __restrict__ beta,
                                                 const unsigned short* __restrict__ x2sb,
                                                 const float* __restrict__ wout,
                                                 float* __restrict__ out) {
    // yA [2][64][72] bf16 (0..18432B) + Bl [128][72] bf16 (18432..36864B);
    // xz [64][148] fp32 (0..37888B) reuses the same region after phase B.
    __shared__ __align__(16) char smem[37888];
    unsigned short* yA = (unsigned short*)smem;
    unsigned short* Bl = (unsigned short*)(smem + 18432);
    float* xz = (float*)smem;
    __shared__ float woutL[4 * 1160];
    __shared__ float gbL[256];
    int t = threadIdx.x;
    for (int idx = t; idx < 4096; idx += 512) {
        int g = idx >> 10, r = idx & 1023, o = r >> 5, i = r & 31;
        woutL[g * 1160 + o * 36 + i] = wout[idx];
    }
    if (t < 128) gbL[t] = gamma[t];
    else if (t < 256) gbL[t] = beta[t - 128];

    // ---- phase A: per-chunk scan replay (1 chunk per (d, ph)), y -> LDS bf16 ----
    int d = t & 127, ph = t >> 7;       // ph in [0,4)
    int b = blockIdx.x >> 6, cblk = blockIdx.x & 63;
    float Ar[8]; bool fast = true;
    #pragma unroll
    for (int n = 0; n < 8; ++n) {
        Ar[n] = -__expf(A_log[d * 8 + n]);
        fast = fast && (fabsf(Ar[n] + (float)(n + 1)) < 2e-3f);
    }
    float Dpr = Dp[d];
    int ybase = (d >> 6) * (64 * 72) + (d & 63);
    {
        int cl = ph;
        int c = cblk * 4 + cl;
        int cbase = ((b * NC_ + c) * 128 + d) * 8;
        float4 ap0 = *(const float4*)&Apre[cbase];
        float4 ap1 = *(const float4*)&Apre[cbase + 4];
        float4 bp0 = *(const float4*)&Bpre[cbase];
        float4 bp1 = *(const float4*)&Bpre[cbase + 4];
        int gbase = (b * 16 + (c >> 4)) * 1024 + d * 8;
        float4 g0 = *(const float4*)&gcar[gbase];
        float4 g1 = *(const float4*)&gcar[gbase + 4];
        float h[8] = { fmaf(g0.x, ap0.x, bp0.x), fmaf(g0.y, ap0.y, bp0.y),
                       fmaf(g0.z, ap0.z, bp0.z), fmaf(g0.w, ap0.w, bp0.w),
                       fmaf(g1.x, ap1.x, bp1.x), fmaf(g1.y, ap1.y, bp1.y),
                       fmaf(g1.z, ap1.z, bp1.z), fmaf(g1.w, ap1.w, bp1.w) };
        int base  = (b * L_ + c * S_) * 128 + d;
        int bbase = (b * L_ + c * S_) * 8;
        #pragma unroll
        for (int s = 0; s < S_; ++s) {
            float dl = bf2f(deltab[base + s * 128]);
            float uv = bf2f(usb[base + s * 128]);
            float zv = bf2f(zb[base + s * 128]);
            float du = dl * uv;
            float4 bm0 = *(const float4*)&Bm[bbase + s * 8];
            float4 bm1 = *(const float4*)&Bm[bbase + s * 8 + 4];
            float4 cm0 = *(const float4*)&Cm[bbase + s * 8];
            float4 cm1 = *(const float4*)&Cm[bbase + s * 8 + 4];
            float a[8];
            scan_as(dl, Ar, fast, a);
            h[0] = a[0] * h[0] + du * bm0.x;
            h[1] = a[1] * h[1] + du * bm0.y;
            h[2] = a[2] * h[2] + du * bm0.z;
            h[3] = a[3] * h[3] + du * bm0.w;
            h[4] = a[4] * h[4] + du * bm1.x;
            h[5] = a[5] * h[5] + du * bm1.y;
            h[6] = a[6] * h[6] + du * bm1.z;
            h[7] = a[7] * h[7] + du * bm1.w;
            float yv = h[0] * cm0.x + h[1] * cm0.y + h[2] * cm0.z + h[3] * cm0.w
                     + h[4] * cm1.x + h[5] * cm1.y + h[6] * cm1.z + h[7] * cm1.w;
            yv = (yv + uv * Dpr) * siluf(zv);
            yA[ybase + (cl * 16 + s) * 72] = f2bf(yv);
        }
    }
    __syncthreads();

    // ---- phase B: out_proj MFMA (64x128), 8 waves: mi=wv&3 rows, nb=(wv>>2)*4 n-tiles ----
    int lane = t & 63, wv = t >> 6;
    int lanem = lane & 15, laneq = lane >> 4;
    int mi = wv & 3, nb = (wv >> 2) * 4;
    f32x4 acc[4];
    #pragma unroll
    for (int i = 0; i < 4; ++i) acc[i] = (f32x4){0.f, 0.f, 0.f, 0.f};
    for (int kc = 0; kc < 2; ++kc) {
        #pragma unroll
        for (int q = 0; q < 2; ++q) {
            int cidx = t + q * 512;
            int row = cidx >> 3, col = cidx & 7;
            *(int4*)&Bl[row * 72 + col * 8] = *(const int4*)&OWb[row * 128 + kc * 64 + col * 8];
        }
        __syncthreads();
        #pragma unroll
        for (int ks = 0; ks < 2; ++ks) {
            short8 af = *(const short8*)&yA[kc * (64 * 72) + (mi * 16 + lanem) * 72 + ks * 32 + laneq * 8];
            #pragma unroll
            for (int ni = 0; ni < 4; ++ni) {
                short8 bfr = *(const short8*)&Bl[((nb + ni) * 16 + lanem) * 72 + ks * 32 + laneq * 8];
                acc[ni] = __builtin_amdgcn_mfma_f32_16x16x32_bf16(af, bfr, acc[ni], 0, 0, 0);
            }
        }
        __syncthreads();   // last iteration: also guards xz overwrite of yA/Bl
    }
    // acc -> xz, rounded through bf16 exactly like round-4. Skewed cols:
    // col = ch + (ch>>5)*4, row stride 148.
    #pragma unroll
    for (int ni = 0; ni < 4; ++ni) {
        int ch = (nb + ni) * 16 + lanem;
        int col = ch + ((ch >> 5) << 2);
        #pragma unroll
        for (int r = 0; r < 4; ++r)
            xz[(mi * 16 + laneq * 4 + r) * 148 + col] = bf2f(f2bf(acc[ni][r]));
    }
    __syncthreads();

    // ---- phases C+D: round-4 VERBATIM (4 thr/row, 64 rows) under t<256 ----
    if (t < 256) {
        int g = t & 3, pos = t >> 2;
        int gpos = b * L_ + cblk * 64 + pos;
        const float* xrow0 = &xz[pos * 148 + g * 36];
        float v[32];
        #pragma unroll
        for (int i4 = 0; i4 < 8; ++i4) {
            float4 xv = *(const float4*)&xrow0[i4 * 4];
            v[i4*4+0] = xv.x; v[i4*4+1] = xv.y;
            v[i4*4+2] = xv.z; v[i4*4+3] = xv.w;
        }
        float s = 0.f, s2 = 0.f;
        #pragma unroll
        for (int i = 0; i < 32; ++i) { s += v[i]; s2 += v[i] * v[i]; }
        s  += __shfl_xor(s, 1, 64);  s  += __shfl_xor(s, 2, 64);
        s2 += __shfl_xor(s2, 1, 64); s2 += __shfl_xor(s2, 2, 64);
        float m = s * (1.f / 128.f);
        float var = s2 * (1.f / 128.f) - m * m;
        float rstd = rsqrtf(var + 1e-5f);
        #pragma unroll
        for (int i4 = 0; i4 < 8; ++i4) {
            ushort4 xv = *(const ushort4*)&x2sb[gpos * 128 + g * 32 + i4 * 4];
            unsigned short xa[4] = {xv.x, xv.y, xv.z, xv.w};
            #pragma unroll
            for (int k = 0; k < 4; ++k) {
                int e = g * 32 + i4 * 4 + k;
                float vv = (v[i4 * 4 + k] - m) * rstd * gbL[e] + gbL[128 + e];
                v[i4 * 4 + k] = vv * bf2f(xa[k]);
            }
        }
        const float* wg = &woutL[g * 1160];
        int obase = gpos * 128 + g * 32;
        #pragma unroll
        for (int ob = 0; ob < 8; ++ob) {
            float o4[4];
            #pragma unroll
            for (int oo = 0; oo < 4; ++oo) {
                int o = ob * 4 + oo;
                float acc2 = 0.f;
                #pragma unroll
                for (int i4 = 0; i4 < 8; ++i4) {
                    float4 wv4 = *(const float4*)&wg[o * 36 + i4 * 4];
                    acc2 += v[i4*4] * wv4.x + v[i4*4+1] * wv4.y
                          + v[i4*4+2] * wv4.z + v[i4*4+3] * wv4.w;
                }
                o4[oo] = acc2;
            }
            *(float4*)&out[obase + ob * 4] = make_float4(o4[0], o4[1], o4[2], o4[3]);
        }
    }
}

extern "C" void kernel_launch(void* const* d_in, const int* in_sizes, int n_in,
                              void* d_out, int out_size, void* d_ws, size_t ws_size,
                              hipStream_t stream) {
    (void)in_sizes; (void)n_in; (void)out_size; (void)ws_size;
    const float* x         = (const float*)d_in[0];
    const float* w1        = (const float*)d_in[1];
    const float* dw        = (const float*)d_in[2];
    const float* in_proj_w = (const float*)d_in[3];
    const float* conv1d_w  = (const float*)d_in[4];
    const float* conv1d_b  = (const float*)d_in[5];
    const float* x_proj_w  = (const float*)d_in[6];
    const float* dt_proj_w = (const float*)d_in[7];
    const float* dt_proj_b = (const float*)d_in[8];
    const float* A_log     = (const float*)d_in[9];
    const float* D_param   = (const float*)d_in[10];
    const float* out_proj_w= (const float*)d_in[11];
    const float* gamma     = (const float*)d_in[12];
    const float* beta      = (const float*)d_in[13];
    const float* w2        = (const float*)d_in[14];
    const float* wout      = (const float*)d_in[15];
    float* out = (float*)d_out;

    float* ws = (float*)d_ws;
    unsigned short* x2sb   = (unsigned short*)(ws);
    unsigned short* t1b    = (unsigned short*)(ws + 2  * (size_t)MFL_);
    unsigned short* x1cb   = (unsigned short*)(ws + 4  * (size_t)MFL_);
    unsigned short* urawb  = (unsigned short*)(ws + 6  * (size_t)MFL_);
    unsigned short* zb     = (unsigned short*)(ws + 8  * (size_t)MFL_);
    unsigned short* usb    = (unsigned short*)(ws + 14 * (size_t)MFL_);
    unsigned short* deltab = (unsigned short*)(ws + 16 * (size_t)MFL_);
    float* Bm    = ws + 18 * (size_t)MFL_;            // 262144
    float* Cm    = Bm + (size_t)NPOS_ * 8;            // 262144
    float* cA    = Cm + (size_t)NPOS_ * 8;            // 2M fl
    float* cB    = cA + 2 * (size_t)MFL_;             // 2M fl
    float* scanw = cB + 2 * (size_t)MFL_;             // reuse old carry region
    float* AgA   = scanw;                             // 131072 fl
    float* AgB   = scanw + 131072;                    // 131072 fl
    float* gcar  = scanw + 262144;                    // 131072 fl
    unsigned short* inWb = (unsigned short*)(scanw + 2 * (size_t)MFL_);
    unsigned short* OWb  = inWb + 32768;
    unsigned short* xpwb = OWb + 16384;

    k1_g1x1<<<1024, 256, 0, stream>>>(x, w1, w2, in_proj_w, out_proj_w, x_proj_w,
                                      inWb, OWb, xpwb, t1b, x2sb);
    k2_dwconv<<<1024, 128, 0, stream>>>(t1b, dw, x1cb);
    k3_mfma<<<1024, 256, 0, stream>>>(x1cb, inWb, urawb, zb);
    k45_convproj<<<1024, 256, 0, stream>>>(urawb, conv1d_w, conv1d_b, xpwb,
                                           dt_proj_w, dt_proj_b, A_log,
                                           usb, deltab, Bm, Cm, cA, cB);
    k6a_scan<<<512, 256, 0, stream>>>(cA, cB, AgA, AgB);
    k6b_scan<<<32, 256, 0, stream>>>(AgA, AgB, gcar);
    k7f_fused<<<512, 512, 0, stream>>>(deltab, usb, Bm, Cm, zb, A_log, D_param,
                                       cA, cB, gcar, OWb, gamma, beta, x2sb, wout, out);
}